// Round 7
// baseline (2136.366 us; speedup 1.0000x reference)
//
#include <hip/hip_runtime.h>
#include <hip/hip_bf16.h>

// Problem constants
#define CIN 256
#define COUT 256
#define HW 56
#define BATCH 8
#define L_SPATIAL 3136            // 56*56
#define K_TOTAL 2304              // CIN*3*3
#define NT 36                     // K chunks of 64
#define TILES_PER_IMG 196
#define GRID 224                  // 1568 / 7 exactly; %8==0 -> XCD-stable
#define TPW 7                     // tiles per workgroup
// A tile: [n][frag][lane][8] u16; n-stride = 2*64*8 = 1024 u16 (NOT 2048 - r6 bug)
#define A_U16 36864               // 36 * 1024
#define STAGE_DW 2340             // 9 groups x 260 dw
#define LDS_BYTES (A_U16 * 2 + 8 * STAGE_DW * 4)   // 73728 + 74880 = 148608
#define BB_STRIDE 40              // u16 per (c,q) row, padded from 36 for 16B alignment
#define ZPLANE (256 * 4 * BB_STRIDE)   // u16 offset of zero-bit plane
#define QMAXF 127.0f
#define QMINF -128.0f

typedef short bf16x8 __attribute__((ext_vector_type(8)));
typedef float f32x4 __attribute__((ext_vector_type(4)));
typedef unsigned int u32x4 __attribute__((ext_vector_type(4)));

// ---- prep: scale[c]=mean|w|; sign bits (w<0) and zero bits (w==0) per (c,q,n) ----
__global__ __launch_bounds__(256) void prep_kernel(
    const float* __restrict__ w, unsigned short* __restrict__ bbits,
    float* __restrict__ scale) {
  const int c = blockIdx.x;
  const int t = threadIdx.x;
  const float* row = w + (size_t)c * K_TOTAL;
  float acc = 0.f;
#pragma unroll
  for (int j = 0; j < 9; ++j) acc += __builtin_fabsf(row[t + 256 * j]);
#pragma unroll
  for (int o = 32; o > 0; o >>= 1) acc += __shfl_down(acc, o, 64);
  __shared__ float red[4];
  if ((t & 63) == 0) red[t >> 6] = acc;
  __syncthreads();
  if (t == 0) scale[c] = (red[0] + red[1] + red[2] + red[3]) * (1.f / 2304.f);
  if (t < 144) {                      // one (q,n) per thread
    const int q = t / 36, n = t - q * 36;
    unsigned int sbits = 0, zbits = 0;
#pragma unroll
    for (int j = 0; j < 8; ++j) {
      const float v0 = row[n * 64 + q * 8 + j];           // frag0
      const float v1 = row[n * 64 + 32 + q * 8 + j];      // frag1
      if (v0 < 0.f) sbits |= (1u << j);
      if (v1 < 0.f) sbits |= (1u << (8 + j));
      if (v0 == 0.f) zbits |= (1u << j);
      if (v1 == 0.f) zbits |= (1u << (8 + j));
    }
    bbits[(c * 4 + q) * BB_STRIDE + n] = (unsigned short)sbits;
    bbits[ZPLANE + (c * 4 + q) * BB_STRIDE + n] = (unsigned short)zbits;
  }
}

// expand 16 sign bits -> two bf16x8 fragments of +-1.0
__device__ __forceinline__ void expand_frags(unsigned int t, bf16x8& b0, bf16x8& b1) {
  u32x4 w0, w1;
#pragma unroll
  for (int d = 0; d < 4; ++d) {
    w0[d] = 0x3F803F80u | ((t & (1u << (2 * d)))     << (15 - 2 * d))
                        | ((t & (1u << (2 * d + 1))) << (30 - 2 * d));
    w1[d] = 0x3F803F80u | ((t & (1u << (8 + 2 * d))) << (7 - 2 * d))
                        | ((t & (1u << (9 + 2 * d))) << (22 - 2 * d));
  }
  b0 = __builtin_bit_cast(bf16x8, w0);
  b1 = __builtin_bit_cast(bf16x8, w1);
}

// K-phase: 36 chunks, VMEM-free (B expanded from regs). Z = rare zero-weight patch.
template <bool Z>
__device__ __forceinline__ void run_k(const unsigned short* __restrict__ abase,
                                      const unsigned int* __restrict__ bb,
                                      const unsigned int* __restrict__ zb,
                                      f32x4* __restrict__ ps, f32x4& sacc) {
  const f32x4 zero = {0.f, 0.f, 0.f, 0.f};
#pragma unroll
  for (int n = 0; n < NT; ++n) {
    const unsigned int td = bb[n >> 1];
    const unsigned int tb = (n & 1) ? (td >> 16) : (td & 0xFFFFu);
    bf16x8 b0, b1;
    expand_frags(tb, b0, b1);
    if (Z) {
      const unsigned int zd = zb[n >> 1];
      const unsigned int zt = (n & 1) ? (zd >> 16) : (zd & 0xFFFFu);
      if (zt) {
        u32x4 w0 = __builtin_bit_cast(u32x4, b0);
        u32x4 w1 = __builtin_bit_cast(u32x4, b1);
#pragma unroll
        for (int d = 0; d < 4; ++d) {
          if (zt & (1u << (2 * d)))     w0[d] &= 0xFFFF0000u;
          if (zt & (1u << (2 * d + 1))) w0[d] &= 0x0000FFFFu;
          if (zt & (1u << (8 + 2 * d))) w1[d] &= 0xFFFF0000u;
          if (zt & (1u << (9 + 2 * d))) w1[d] &= 0x0000FFFFu;
        }
        b0 = __builtin_bit_cast(bf16x8, w0);
        b1 = __builtin_bit_cast(bf16x8, w1);
      }
    }
    bf16x8 a0 = *reinterpret_cast<const bf16x8*>(abase + n * 1024);
    bf16x8 a1 = *reinterpret_cast<const bf16x8*>(abase + n * 1024 + 512);
    f32x4 acc = __builtin_amdgcn_mfma_f32_16x16x32_bf16(a0, b0, zero, 0, 0, 0);
    acc = __builtin_amdgcn_mfma_f32_16x16x32_bf16(a1, b1, acc, 0, 0, 0);
    ps[n] = acc;
    if (n == 0) sacc = acc;                 // scan carry starts UNCLIPPED (matches ref)
    else {
#pragma unroll
      for (int e = 0; e < 4; ++e) {
        const float tv = sacc[e] + acc[e];
        sacc[e] = __builtin_amdgcn_fmed3f(tv, QMINF, QMAXF);
      }
    }
  }
}

// ---- main: persistent 512-thr WGs, 7 tiles each; VMEM-free K-loop; raw barriers ----
__global__ __launch_bounds__(512, 2) void satconv_kernel(
    const float* __restrict__ x, const unsigned short* __restrict__ bbits,
    const float* __restrict__ scale, float* __restrict__ y_out,
    float* __restrict__ psum_out) {
  extern __shared__ char smem[];
  unsigned short* Atile = (unsigned short*)smem;             // frag-order A (73,728 B)
  float* stage_base = (float*)(smem + A_U16 * 2);

  const int tid = threadIdx.x;
  const int lane = tid & 63;
  const int wave = tid >> 6;                                 // 0..7
  const int cl = lane & 15;
  const int q = lane >> 4;
  const int c0 = wave << 5;                                  // 32 couts per wave
  float* stage = stage_base + wave * STAGE_DW;
  const int w_id = blockIdx.x;

  auto load_bb = [&](const unsigned short* plane, int s, unsigned int* bb) {
    const unsigned short* bp = plane + (size_t)((c0 + (s << 4) + cl) * 4 + q) * BB_STRIDE;
    const uint4* p4 = (const uint4*)bp;
    uint4 v0 = p4[0], v1 = p4[1], v2 = p4[2], v3 = p4[3];
    uint2 v4 = *(const uint2*)(bp + 32);
    bb[0]=v0.x; bb[1]=v0.y; bb[2]=v0.z; bb[3]=v0.w;
    bb[4]=v1.x; bb[5]=v1.y; bb[6]=v1.z; bb[7]=v1.w;
    bb[8]=v2.x; bb[9]=v2.y; bb[10]=v2.z; bb[11]=v2.w;
    bb[12]=v3.x; bb[13]=v3.y; bb[14]=v3.z; bb[15]=v3.w;
    bb[16]=v4.x; bb[17]=v4.y;
  };

  // im2col loads for a tile -> bf16 packed into 36 dwords held in regs
  auto load_pack = [&](int m0n, unsigned int* apack) {
    const int ml = tid & 15;
    const int grp = tid >> 4;                                // 0..31
    const int m = m0n + ml;
    const int b = m / L_SPATIAL;
    const int l = m - b * L_SPATIAL;
    const int oh = l / HW, ow = l - oh * HW;
    const float* xb = x + (size_t)b * (CIN * L_SPATIAL);
#pragma unroll
    for (int j = 0; j < 24; ++j) {
      const int r = grp + 32 * j;                            // r = ci*3+kh
      const int ci = r / 3, kh = r - ci * 3;
      const int h = oh + kh - 1;
      const bool hv = ((unsigned)h < (unsigned)HW);
      const float* xr = xb + (ci * HW + h) * HW;
#pragma unroll
      for (int kw = 0; kw < 3; ++kw) {
        const int wv = ow + kw - 1;
        float v = 0.f;
        if (hv && ((unsigned)wv < (unsigned)HW)) v = xr[wv];
        __hip_bfloat16 bv = __float2bfloat16(v);
        unsigned int u = (unsigned int)*reinterpret_cast<unsigned short*>(&bv);
        const int idx = j * 3 + kw;
        if (idx & 1) apack[idx >> 1] |= (u << 16);
        else         apack[idx >> 1] = u;
      }
    }
  };

  auto unpack_write = [&](const unsigned int* apack) {
    const int ml = tid & 15;
    const int grp = tid >> 4;
#pragma unroll
    for (int j = 0; j < 24; ++j) {
      const int r = grp + 32 * j;
      const int ci = r / 3, kh = r - ci * 3;
      const int kb = ci * 9 + kh * 3;
#pragma unroll
      for (int kw = 0; kw < 3; ++kw) {
        const int idx = j * 3 + kw;
        unsigned int u = apack[idx >> 1];
        u = (idx & 1) ? (u >> 16) : (u & 0xFFFFu);
        const int k = kb + kw;
        // [n][frag][lane=(kq*16+ml)][j]: n-stride 1024 u16, frag-stride 512 u16
        const int addr = ((k >> 6) << 10) + (((k >> 5) & 1) << 9)
                       + ((((k >> 3) & 3) * 16 + ml) << 3) + (k & 7);
        Atile[addr] = (unsigned short)u;
      }
    }
  };

  unsigned int bb0[18];
  load_bb(bbits, 0, bb0);
  const float sc0 = scale[c0 + cl];
  const float sc1 = scale[c0 + 16 + cl];

  // hoisted zero-weight detection (almost always false -> fast path, no zb regs)
  bool zany0, zany1;
  {
    unsigned int zt0[18], zt1[18];
    load_bb(bbits + ZPLANE, 0, zt0);
    load_bb(bbits + ZPLANE, 1, zt1);
    unsigned int o0 = 0, o1 = 0;
#pragma unroll
    for (int i = 0; i < 18; ++i) { o0 |= zt0[i]; o1 |= zt1[i]; }
    zany0 = __any(o0 != 0);
    zany1 = __any(o1 != 0);
  }

  // prologue: build A for first tile
  {
    unsigned int ap[36];
    const int t0 = ((w_id & 7) * TILES_PER_IMG + (w_id >> 3)) << 4;
    load_pack(t0, ap);
    unpack_write(ap);
  }
  __asm__ volatile("s_waitcnt lgkmcnt(0)\ns_barrier" ::: "memory");

  const unsigned short* abase = Atile + lane * 8;

  int tt = w_id;
  for (int i = 0; i < TPW; ++i, tt += GRID) {
    const int t = (tt & 7) * TILES_PER_IMG + (tt >> 3);
    const int m0 = t << 4;
    const int b_img = tt & 7;
    const int l0 = m0 - b_img * L_SPATIAL;

    auto stage_store = [&](int s, f32x4* ps, f32x4 sacc, float sc) {
      const int csub0 = c0 + (s << 4);
      // y: 16c x 16m block, full 64B-line stores
      f32x4 yv;
#pragma unroll
      for (int e = 0; e < 4; ++e) yv[e] = sacc[e] * sc;
      *reinterpret_cast<f32x4*>(stage + cl * 16 + q * 4) = yv;
      {
        const int ci = lane >> 2, mi = (lane & 3) << 2;
        f32x4 v = *reinterpret_cast<const f32x4*>(stage + lane * 4);
        *reinterpret_cast<f32x4*>(
            y_out + ((size_t)b_img * COUT + csub0 + ci) * L_SPATIAL + l0 + mi) = v;
      }
      // psum: per-rg transpose through stage; dense 16B/lane writes, 1KB store bursts
      const int qc4 = (q * 16 + cl) * 4;
#pragma unroll
      for (int rg = 0; rg < 4; ++rg) {
#pragma unroll
        for (int g = 0; g < 9; ++g) {
          f32x4 v = {ps[4 * g + 0][rg], ps[4 * g + 1][rg],
                     ps[4 * g + 2][rg], ps[4 * g + 3][rg]};
          *reinterpret_cast<f32x4*>(stage + g * 260 + qc4) = v;
        }
#pragma unroll
        for (int it = 0; it < 9; ++it) {
          const int f = it * 256 + lane * 4;
          const int qq = f / 576;
          const int rem = f - qq * 576;
          const int ci = rem / 36;
          const int n0 = rem - ci * 36;          // always %4==0
          f32x4 v = *reinterpret_cast<const f32x4*>(
              stage + (n0 >> 2) * 260 + (qq * 16 + ci) * 4);
          const int goff = ((m0 + (qq << 2) + rg) * COUT + (csub0 + ci)) * NT + n0;
          *reinterpret_cast<f32x4*>(psum_out + goff) = v;
        }
      }
    };

    // ---- K s=0 (VMEM-free) ----
    f32x4 ps0[NT];
    f32x4 sacc0;
    if (zany0) {
      unsigned int zb[18];
      load_bb(bbits + ZPLANE, 0, zb);
      run_k<true>(abase, bb0, zb, ps0, sacc0);
    } else {
      run_k<false>(abase, bb0, nullptr, ps0, sacc0);
    }

    // ---- issue loads (bb s=1 + next-tile x) BEFORE the store stream (vmcnt in-order) ----
    unsigned int bb1[18];
    load_bb(bbits, 1, bb1);
    unsigned int apack[36];
    const bool more = (i + 1 < TPW);
    if (more) {
      const int tn = tt + GRID;
      load_pack(((tn & 7) * TILES_PER_IMG + (tn >> 3)) << 4, apack);
    }
    __asm__ volatile("" ::: "memory");

    stage_store(0, ps0, sacc0, sc0);

    // ---- K s=1 (stores from s0 drain in background) ----
    f32x4 ps1[NT];
    f32x4 sacc1;
    if (zany1) {
      unsigned int zb[18];
      load_bb(bbits + ZPLANE, 1, zb);
      run_k<true>(abase, bb1, zb, ps1, sacc1);
    } else {
      run_k<false>(abase, bb1, nullptr, ps1, sacc1);
    }

    // ---- raw barriers (no vmcnt drain): rebuild A for next tile ----
    __asm__ volatile("s_barrier" ::: "memory");          // all waves done reading A
    if (more) unpack_write(apack);
    __asm__ volatile("s_waitcnt lgkmcnt(0)\ns_barrier" ::: "memory");

    stage_store(1, ps1, sacc1, sc1);
  }
}

extern "C" void kernel_launch(void* const* d_in, const int* in_sizes, int n_in,
                              void* d_out, int out_size, void* d_ws, size_t ws_size,
                              hipStream_t stream) {
  const float* x = (const float*)d_in[0];
  const float* w = (const float*)d_in[1];
  float* y = (float*)d_out;
  float* psum = y + (size_t)BATCH * COUT * L_SPATIAL;
  unsigned short* bbits = (unsigned short*)d_ws;   // 2 planes x 81,920 B
  float* scale = (float*)((char*)d_ws + 2 * ZPLANE * sizeof(unsigned short));

  prep_kernel<<<COUT, 256, 0, stream>>>(w, bbits, scale);

  hipFuncSetAttribute(reinterpret_cast<const void*>(satconv_kernel),
                      hipFuncAttributeMaxDynamicSharedMemorySize, LDS_BYTES);
  satconv_kernel<<<GRID, 512, LDS_BYTES, stream>>>(x, bbits, scale, y, psum);
}

// Round 8
// 2082.144 us; speedup vs baseline: 1.0260x; 1.0260x over previous
//
#include <hip/hip_runtime.h>
#include <hip/hip_bf16.h>

// Problem constants
#define CIN 256
#define COUT 256
#define HW 56
#define BATCH 8
#define L_SPATIAL 3136            // 56*56
#define K_TOTAL 2304              // CIN*3*3
#define NT 36                     // K chunks of 64
#define TILES_PER_IMG 196
#define GRID 256                  // all CUs; w<32 -> 7 tiles, else 6 (4*7+28*6=196/image)
// A tile: [n][frag][lane][8] u16; n-stride = 2*64*8 = 1024 u16
#define A_U16 36864               // 36 * 1024
#define STAGE_DW 2340             // 9 groups x 260 dw
#define LDS_BYTES (A_U16 * 2 + 8 * STAGE_DW * 4)   // 73728 + 74880 = 148608
#define BB_STRIDE 48              // u16 per (c,q) row; 96 B -> every row 16B-aligned
#define ZPLANE (256 * 4 * BB_STRIDE)   // u16 offset of zero-bit plane
#define QMAXF 127.0f
#define QMINF -128.0f

typedef short bf16x8 __attribute__((ext_vector_type(8)));
typedef float f32x4 __attribute__((ext_vector_type(4)));
typedef unsigned int u32x4 __attribute__((ext_vector_type(4)));

// ---- prep: scale[c]=mean|w|; sign bits (w<0) and zero bits (w==0) per (c,q,n) ----
__global__ __launch_bounds__(256) void prep_kernel(
    const float* __restrict__ w, unsigned short* __restrict__ bbits,
    float* __restrict__ scale) {
  const int c = blockIdx.x;
  const int t = threadIdx.x;
  const float* row = w + (size_t)c * K_TOTAL;
  float acc = 0.f;
#pragma unroll
  for (int j = 0; j < 9; ++j) acc += __builtin_fabsf(row[t + 256 * j]);
#pragma unroll
  for (int o = 32; o > 0; o >>= 1) acc += __shfl_down(acc, o, 64);
  __shared__ float red[4];
  if ((t & 63) == 0) red[t >> 6] = acc;
  __syncthreads();
  if (t == 0) scale[c] = (red[0] + red[1] + red[2] + red[3]) * (1.f / 2304.f);
  if (t < 144) {                      // one (q,n) per thread
    const int q = t / 36, n = t - q * 36;
    unsigned int sbits = 0, zbits = 0;
#pragma unroll
    for (int j = 0; j < 8; ++j) {
      const float v0 = row[n * 64 + q * 8 + j];           // frag0
      const float v1 = row[n * 64 + 32 + q * 8 + j];      // frag1
      if (v0 < 0.f) sbits |= (1u << j);
      if (v1 < 0.f) sbits |= (1u << (8 + j));
      if (v0 == 0.f) zbits |= (1u << j);
      if (v1 == 0.f) zbits |= (1u << (8 + j));
    }
    bbits[(c * 4 + q) * BB_STRIDE + n] = (unsigned short)sbits;
    bbits[ZPLANE + (c * 4 + q) * BB_STRIDE + n] = (unsigned short)zbits;
  }
}

// expand 16 sign bits -> two bf16x8 fragments of +-1.0
__device__ __forceinline__ void expand_frags(unsigned int t, bf16x8& b0, bf16x8& b1) {
  u32x4 w0, w1;
#pragma unroll
  for (int d = 0; d < 4; ++d) {
    w0[d] = 0x3F803F80u | ((t & (1u << (2 * d)))     << (15 - 2 * d))
                        | ((t & (1u << (2 * d + 1))) << (30 - 2 * d));
    w1[d] = 0x3F803F80u | ((t & (1u << (8 + 2 * d))) << (7 - 2 * d))
                        | ((t & (1u << (9 + 2 * d))) << (22 - 2 * d));
  }
  b0 = __builtin_bit_cast(bf16x8, w0);
  b1 = __builtin_bit_cast(bf16x8, w1);
}

// K-phase: 36 chunks, VMEM-free. ps[n] pinned to AGPRs (no scratch spill).
template <bool Z>
__device__ __forceinline__ void run_k(const unsigned short* abase,
                                      const unsigned int* bb,
                                      const unsigned int* zb,
                                      f32x4* ps, f32x4& sacc) {
  const f32x4 zero = {0.f, 0.f, 0.f, 0.f};
#pragma unroll
  for (int n = 0; n < NT; ++n) {
    const unsigned int td = bb[n >> 1];
    const unsigned int tb = (n & 1) ? (td >> 16) : (td & 0xFFFFu);
    bf16x8 b0, b1;
    expand_frags(tb, b0, b1);
    if (Z) {
      const unsigned int zd = zb[n >> 1];
      const unsigned int zt = (n & 1) ? (zd >> 16) : (zd & 0xFFFFu);
      if (zt) {
        u32x4 w0 = __builtin_bit_cast(u32x4, b0);
        u32x4 w1 = __builtin_bit_cast(u32x4, b1);
#pragma unroll
        for (int d = 0; d < 4; ++d) {
          if (zt & (1u << (2 * d)))     w0[d] &= 0xFFFF0000u;
          if (zt & (1u << (2 * d + 1))) w0[d] &= 0x0000FFFFu;
          if (zt & (1u << (8 + 2 * d))) w1[d] &= 0xFFFF0000u;
          if (zt & (1u << (9 + 2 * d))) w1[d] &= 0x0000FFFFu;
        }
        b0 = __builtin_bit_cast(bf16x8, w0);
        b1 = __builtin_bit_cast(bf16x8, w1);
      }
    }
    bf16x8 a0 = *reinterpret_cast<const bf16x8*>(abase + n * 1024);
    bf16x8 a1 = *reinterpret_cast<const bf16x8*>(abase + n * 1024 + 512);
    f32x4 acc = __builtin_amdgcn_mfma_f32_16x16x32_bf16(a0, b0, zero, 0, 0, 0);
    acc = __builtin_amdgcn_mfma_f32_16x16x32_bf16(a1, b1, acc, 0, 0, 0);
    // scan in VGPR domain (carry starts UNCLIPPED at n==0, matches ref)
    if (n == 0) sacc = acc;
    else {
#pragma unroll
      for (int e = 0; e < 4; ++e) {
        const float tv = sacc[e] + acc[e];
        sacc[e] = __builtin_amdgcn_fmed3f(tv, QMINF, QMAXF);
      }
    }
    // pin psum fragment into AGPR class: 36 x f32x4 = 144 AGPRs, zero scratch
    asm volatile("" : "+a"(acc));
    ps[n] = acc;
  }
}

// ---- main: persistent 512-thr WGs; AGPR psums; VMEM-free K; raw barriers ----
__global__ __launch_bounds__(512, 2) void satconv_kernel(
    const float* __restrict__ x, const unsigned short* __restrict__ bbits,
    const float* __restrict__ scale, float* __restrict__ y_out,
    float* __restrict__ psum_out) {
  extern __shared__ char smem[];
  unsigned short* Atile = (unsigned short*)smem;             // frag-order A (73,728 B)
  float* stage_base = (float*)(smem + A_U16 * 2);

  const int tid = threadIdx.x;
  const int lane = tid & 63;
  const int wave = tid >> 6;                                 // 0..7
  const int cl = lane & 15;
  const int q = lane >> 4;
  const int c0 = wave << 5;                                  // 32 couts per wave
  float* stage = stage_base + wave * STAGE_DW;
  const int w_id = blockIdx.x;
  const int ntiles = (w_id < 32) ? 7 : 6;

  auto load_bb = [&](const unsigned short* plane, int s, unsigned int* bb) {
    const unsigned short* bp = plane + (size_t)((c0 + (s << 4) + cl) * 4 + q) * BB_STRIDE;
    const uint4* p4 = (const uint4*)bp;                      // rows 96B -> 16B-aligned
    uint4 v0 = p4[0], v1 = p4[1], v2 = p4[2], v3 = p4[3];
    uint2 v4 = *(const uint2*)(bp + 32);
    bb[0]=v0.x; bb[1]=v0.y; bb[2]=v0.z; bb[3]=v0.w;
    bb[4]=v1.x; bb[5]=v1.y; bb[6]=v1.z; bb[7]=v1.w;
    bb[8]=v2.x; bb[9]=v2.y; bb[10]=v2.z; bb[11]=v2.w;
    bb[12]=v3.x; bb[13]=v3.y; bb[14]=v3.z; bb[15]=v3.w;
    bb[16]=v4.x; bb[17]=v4.y;
  };

  // im2col loads for a tile -> bf16 packed into 36 dwords held in regs
  auto load_pack = [&](int m0n, unsigned int* apack) {
    const int ml = tid & 15;
    const int grp = tid >> 4;                                // 0..31
    const int m = m0n + ml;
    const int b = m / L_SPATIAL;
    const int l = m - b * L_SPATIAL;
    const int oh = l / HW, ow = l - oh * HW;
    const float* xb = x + (size_t)b * (CIN * L_SPATIAL);
#pragma unroll
    for (int j = 0; j < 24; ++j) {
      const int r = grp + 32 * j;                            // r = ci*3+kh
      const int ci = r / 3, kh = r - ci * 3;
      const int h = oh + kh - 1;
      const bool hv = ((unsigned)h < (unsigned)HW);
      const float* xr = xb + (ci * HW + h) * HW;
#pragma unroll
      for (int kw = 0; kw < 3; ++kw) {
        const int wv = ow + kw - 1;
        float v = 0.f;
        if (hv && ((unsigned)wv < (unsigned)HW)) v = xr[wv];
        __hip_bfloat16 bv = __float2bfloat16(v);
        unsigned int u = (unsigned int)*reinterpret_cast<unsigned short*>(&bv);
        const int idx = j * 3 + kw;
        if (idx & 1) apack[idx >> 1] |= (u << 16);
        else         apack[idx >> 1] = u;
      }
    }
  };

  auto unpack_write = [&](const unsigned int* apack) {
    const int ml = tid & 15;
    const int grp = tid >> 4;
#pragma unroll
    for (int j = 0; j < 24; ++j) {
      const int r = grp + 32 * j;
      const int ci = r / 3, kh = r - ci * 3;
      const int kb = ci * 9 + kh * 3;
#pragma unroll
      for (int kw = 0; kw < 3; ++kw) {
        const int idx = j * 3 + kw;
        unsigned int u = apack[idx >> 1];
        u = (idx & 1) ? (u >> 16) : (u & 0xFFFFu);
        const int k = kb + kw;
        // [n][frag][lane=(kq*16+ml)][j]: n-stride 1024 u16, frag-stride 512 u16
        const int addr = ((k >> 6) << 10) + (((k >> 5) & 1) << 9)
                       + ((((k >> 3) & 3) * 16 + ml) << 3) + (k & 7);
        Atile[addr] = (unsigned short)u;
      }
    }
  };

  unsigned int bb0[18];
  load_bb(bbits, 0, bb0);
  const float sc0 = scale[c0 + cl];
  const float sc1 = scale[c0 + 16 + cl];

  // hoisted zero-weight detection (almost always false -> fast path)
  bool zany0, zany1;
  {
    unsigned int zt0[18], zt1[18];
    load_bb(bbits + ZPLANE, 0, zt0);
    load_bb(bbits + ZPLANE, 1, zt1);
    unsigned int o0 = 0, o1 = 0;
#pragma unroll
    for (int i = 0; i < 18; ++i) { o0 |= zt0[i]; o1 |= zt1[i]; }
    zany0 = __any(o0 != 0);
    zany1 = __any(o1 != 0);
  }

  // prologue: build A for first tile
  {
    unsigned int ap[36];
    const int t0 = ((w_id & 7) * TILES_PER_IMG + (w_id >> 3)) << 4;
    load_pack(t0, ap);
    unpack_write(ap);
  }
  __asm__ volatile("s_waitcnt lgkmcnt(0)\ns_barrier" ::: "memory");

  const unsigned short* abase = Atile + lane * 8;

  int tt = w_id;
  for (int i = 0; i < ntiles; ++i, tt += GRID) {
    const int t = (tt & 7) * TILES_PER_IMG + (tt >> 3);
    const int m0 = t << 4;
    const int b_img = tt & 7;
    const int l0 = m0 - b_img * L_SPATIAL;

    auto stage_store = [&](int s, f32x4* ps, f32x4 sacc, float sc) {
      const int csub0 = c0 + (s << 4);
      // y: 16c x 16m block, 64B-chunk stores
      f32x4 yv;
#pragma unroll
      for (int e = 0; e < 4; ++e) yv[e] = sacc[e] * sc;
      *reinterpret_cast<f32x4*>(stage + cl * 16 + q * 4) = yv;
      {
        const int ci = lane >> 2, mi = (lane & 3) << 2;
        f32x4 v = *reinterpret_cast<const f32x4*>(stage + lane * 4);
        *reinterpret_cast<f32x4*>(
            y_out + ((size_t)b_img * COUT + csub0 + ci) * L_SPATIAL + l0 + mi) = v;
      }
      // psum: per-rg transpose through stage; dense 2304B-aligned full-line bursts
      const int qc4 = (q * 16 + cl) * 4;
#pragma unroll
      for (int rg = 0; rg < 4; ++rg) {
#pragma unroll
        for (int g = 0; g < 9; ++g) {
          f32x4 v = {ps[4 * g + 0][rg], ps[4 * g + 1][rg],
                     ps[4 * g + 2][rg], ps[4 * g + 3][rg]};
          *reinterpret_cast<f32x4*>(stage + g * 260 + qc4) = v;
        }
#pragma unroll
        for (int it = 0; it < 9; ++it) {
          const int f = it * 256 + lane * 4;
          const int qq = f / 576;
          const int rem = f - qq * 576;
          const int ci = rem / 36;
          const int n0 = rem - ci * 36;          // always %4==0
          f32x4 v = *reinterpret_cast<const f32x4*>(
              stage + (n0 >> 2) * 260 + (qq * 16 + ci) * 4);
          const int goff = ((m0 + (qq << 2) + rg) * COUT + (csub0 + ci)) * NT + n0;
          *reinterpret_cast<f32x4*>(psum_out + goff) = v;
        }
      }
    };

    // ---- K s=0 (VMEM-free; psums land in AGPRs) ----
    f32x4 ps0[NT];
    f32x4 sacc0;
    if (zany0) {
      unsigned int zb[18];
      load_bb(bbits + ZPLANE, 0, zb);
      run_k<true>(abase, bb0, zb, ps0, sacc0);
    } else {
      run_k<false>(abase, bb0, nullptr, ps0, sacc0);
    }

    // ---- issue loads (bb s=1 + next-tile x) BEFORE the store stream ----
    // (vmcnt retires in order: consuming these later only waits on loads,
    //  leaving the psum store queue in flight)
    unsigned int bb1[18];
    load_bb(bbits, 1, bb1);
    unsigned int apack[36];
    const bool more = (i + 1 < ntiles);
    if (more) {
      const int tn = tt + GRID;
      load_pack(((tn & 7) * TILES_PER_IMG + (tn >> 3)) << 4, apack);
    }
    __asm__ volatile("" ::: "memory");

    stage_store(0, ps0, sacc0, sc0);

    // ---- K s=1 (stores from s0 drain in background) ----
    f32x4 ps1[NT];
    f32x4 sacc1;
    if (zany1) {
      unsigned int zb[18];
      load_bb(bbits + ZPLANE, 1, zb);
      run_k<true>(abase, bb1, zb, ps1, sacc1);
    } else {
      run_k<false>(abase, bb1, nullptr, ps1, sacc1);
    }

    // ---- raw barriers (no vmcnt drain): rebuild A for next tile ----
    __asm__ volatile("s_barrier" ::: "memory");          // all waves done reading A
    if (more) unpack_write(apack);
    __asm__ volatile("s_waitcnt lgkmcnt(0)\ns_barrier" ::: "memory");

    stage_store(1, ps1, sacc1, sc1);
  }
}

extern "C" void kernel_launch(void* const* d_in, const int* in_sizes, int n_in,
                              void* d_out, int out_size, void* d_ws, size_t ws_size,
                              hipStream_t stream) {
  const float* x = (const float*)d_in[0];
  const float* w = (const float*)d_in[1];
  float* y = (float*)d_out;
  float* psum = y + (size_t)BATCH * COUT * L_SPATIAL;
  unsigned short* bbits = (unsigned short*)d_ws;   // 2 planes x 98,304 B
  float* scale = (float*)((char*)d_ws + 2 * ZPLANE * sizeof(unsigned short));

  prep_kernel<<<COUT, 256, 0, stream>>>(w, bbits, scale);

  hipFuncSetAttribute(reinterpret_cast<const void*>(satconv_kernel),
                      hipFuncAttributeMaxDynamicSharedMemorySize, LDS_BYTES);
  satconv_kernel<<<GRID, 512, LDS_BYTES, stream>>>(x, bbits, scale, y, psum);
}